// Round 1
// baseline (44.403 us; speedup 1.0000x reference)
//
#include <hip/hip_runtime.h>

// ToRMS: sliding RMS energy, frame=2048, hop=512, pad=1024 each side.
// y: (64, 960000) f32  ->  out: (64, 1876) f32
//
// Decomposition: frame sum = sum of 4 consecutive 512-sample chunk sums
// (2048/512 == 4, hop-aligned). Stage per-chunk sum-of-squares in d_ws.

#define FRAME   2048
#define HOP     512
#define NROWS   64
#define NCOLS   960000
#define CHUNKS  1875          // NCOLS / HOP (chunks never cross a row: 960000 % 512 == 0)
#define TOUT    1876          // (NCOLS + 2*1024 - FRAME)/HOP + 1
#define TOTAL_CHUNKS (NROWS * CHUNKS)   // 120000
#define TOTAL_OUT    (NROWS * TOUT)     // 120064

// Kernel 1: one wave (64 lanes) per 512-float chunk.
// Lane i loads float4 at [i] and [i+64] (two coalesced 1 KiB wave transactions),
// squares + sums 8 elements locally, then 6-step shfl_xor reduce.
__global__ __launch_bounds__(256) void chunk_sumsq(const float* __restrict__ y,
                                                   float* __restrict__ S) {
    const int lane   = threadIdx.x & 63;
    const int wave   = (blockIdx.x * blockDim.x + threadIdx.x) >> 6;
    const int nwaves = (gridDim.x * blockDim.x) >> 6;

    for (int c = wave; c < TOTAL_CHUNKS; c += nwaves) {
        const float4* p = reinterpret_cast<const float4*>(y + (size_t)c * HOP);
        float4 a = p[lane];
        float4 b = p[lane + 64];
        float s = a.x * a.x + a.y * a.y + a.z * a.z + a.w * a.w
                + b.x * b.x + b.y * b.y + b.z * b.z + b.w * b.w;
        #pragma unroll
        for (int off = 32; off; off >>= 1)
            s += __shfl_xor(s, off, 64);
        if (lane == 0) S[c] = s;
    }
}

// Kernel 2: out[row][t] = sqrt( (S[t-2] + S[t-1] + S[t] + S[t+1]) / 2048 )
// with out-of-range chunk sums (the zero padding) contributing 0.
__global__ __launch_bounds__(256) void rms_out(const float* __restrict__ S,
                                               float* __restrict__ out) {
    const int idx = blockIdx.x * blockDim.x + threadIdx.x;
    if (idx >= TOTAL_OUT) return;
    const int row = idx / TOUT;
    const int t   = idx - row * TOUT;
    const float* Sr = S + row * CHUNKS;

    float s = 0.0f;
    #pragma unroll
    for (int k = 0; k < 4; ++k) {
        const int c = t + k - 2;
        if (c >= 0 && c < CHUNKS) s += Sr[c];
    }
    out[idx] = sqrtf(s * (1.0f / (float)FRAME));
}

extern "C" void kernel_launch(void* const* d_in, const int* in_sizes, int n_in,
                              void* d_out, int out_size, void* d_ws, size_t ws_size,
                              hipStream_t stream) {
    const float* y = (const float*)d_in[0];
    float* out = (float*)d_out;
    float* S   = (float*)d_ws;   // 120000 floats = 480 KB of scratch

    // Kernel 1: grid-stride, ~2048 blocks x 256 threads (4 waves/block).
    chunk_sumsq<<<2048, 256, 0, stream>>>(y, S);

    // Kernel 2: tiny epilogue.
    rms_out<<<(TOTAL_OUT + 255) / 256, 256, 0, stream>>>(S, out);
}

// Round 3
// 41.541 us; speedup vs baseline: 1.0689x; 1.0689x over previous
//
#include <hip/hip_runtime.h>

// ToRMS fused: sliding RMS energy, frame=2048, hop=512, pad=1024 each side.
// y: (64, 960000) f32  ->  out: (64, 1876) f32
//
// frame sum = sum of 4 consecutive 512-sample chunk sums (2048/512 == 4).
// Fused single kernel: each block owns T=128 output frames of one row,
// computes the <=131 chunk sums it needs into LDS (3-chunk halo, +2.3%
// redundant fetch), then 4-tap sum + sqrt from LDS. No scratch round-trip,
// no second launch.

#define FRAME   2048
#define HOP     512
#define NROWS   64
#define NCOLS   960000
#define CHUNKS  1875          // NCOLS / HOP (chunks never cross a row)
#define TOUT    1876          // (NCOLS + 2*1024 - FRAME)/HOP + 1
#define TBLK    128           // output frames per block
#define SEGS    15            // ceil(TOUT / TBLK)
#define CMAX    (TBLK + 3)    // max chunks a block needs

typedef float f32x4 __attribute__((ext_vector_type(4)));  // native vector type:
// __builtin_nontemporal_load requires scalar/native-vector pointee (not HIP_vector_type).

__global__ __launch_bounds__(256) void rms_fused(const float* __restrict__ y,
                                                 float* __restrict__ out) {
    __shared__ float Ssm[CMAX];

    const int row = blockIdx.x / SEGS;
    const int seg = blockIdx.x - row * SEGS;
    const int t0  = seg * TBLK;
    const int t1  = (t0 + TBLK < TOUT) ? (t0 + TBLK) : TOUT;
    const int cLo = t0 - 2;               // first chunk index needed (may be <0)
    const int nch = (t1 + 1) - cLo + 1;   // chunks [cLo, t1+1] inclusive

    const int lane = threadIdx.x & 63;
    const int wave = threadIdx.x >> 6;    // 4 waves per block

    const float* yrow = y + (size_t)row * NCOLS;

    // Phase 1: each wave computes chunk sums round-robin into LDS.
    for (int j = wave; j < nch; j += 4) {
        const int c = cLo + j;
        float s = 0.0f;
        if (c >= 0 && c < CHUNKS) {
            const f32x4* p = reinterpret_cast<const f32x4*>(yrow + (size_t)c * HOP);
            f32x4 a = __builtin_nontemporal_load(p + lane);
            f32x4 b = __builtin_nontemporal_load(p + lane + 64);
            s = a.x * a.x + a.y * a.y + a.z * a.z + a.w * a.w
              + b.x * b.x + b.y * b.y + b.z * b.z + b.w * b.w;
            #pragma unroll
            for (int off = 32; off; off >>= 1)
                s += __shfl_xor(s, off, 64);
        }
        if (lane == 0) Ssm[j] = s;
    }
    __syncthreads();

    // Phase 2: out[t] = sqrt((S[t-2]+S[t-1]+S[t]+S[t+1]) / 2048).
    // Chunk t-2 sits at LDS index (t - t0).
    const int t = t0 + threadIdx.x;
    if (threadIdx.x < TBLK && t < t1) {
        const int j = t - t0;
        float s = Ssm[j] + Ssm[j + 1] + Ssm[j + 2] + Ssm[j + 3];
        out[(size_t)row * TOUT + t] = sqrtf(s * (1.0f / (float)FRAME));
    }
}

extern "C" void kernel_launch(void* const* d_in, const int* in_sizes, int n_in,
                              void* d_out, int out_size, void* d_ws, size_t ws_size,
                              hipStream_t stream) {
    const float* y = (const float*)d_in[0];
    float* out = (float*)d_out;
    rms_fused<<<NROWS * SEGS, 256, 0, stream>>>(y, out);
}